// Round 3
// baseline (385.256 us; speedup 1.0000x reference)
//
#include <hip/hip_runtime.h>
#include <math.h>

typedef long long i64;

// ---------------- CSR build ----------------

__global__ void k_init(int* __restrict__ deg, int* __restrict__ fill, int N) {
    int i = blockIdx.x * blockDim.x + threadIdx.x;
    if (i < N) { deg[i] = 1; fill[i] = 0; }   // deg starts at 1 (self-loop)
}

__global__ void k_count(const int* __restrict__ ei, int E, int* __restrict__ deg, int N) {
    int e = blockIdx.x * blockDim.x + threadIdx.x;
    if (e < E) {
        int d = ei[E + e];          // dst row
        if (d >= 0 && d < N) atomicAdd(&deg[d], 1);
    }
}

// per-1024-tile sums of (deg-1) + dinv computation
__global__ void k_blocksum(const int* __restrict__ deg, float* __restrict__ dinv,
                           int* __restrict__ bsum, int N) {
    __shared__ int sdata[256];
    int t = threadIdx.x, b = blockIdx.x;
    int base = b * 1024 + t * 4;
    int s = 0;
    #pragma unroll
    for (int i = 0; i < 4; i++) {
        int idx = base + i;
        if (idx < N) {
            int d = deg[idx];
            s += d - 1;
            dinv[idx] = rsqrtf((float)d);
        }
    }
    sdata[t] = s; __syncthreads();
    for (int off = 128; off > 0; off >>= 1) {
        if (t < off) sdata[t] += sdata[t + off];
        __syncthreads();
    }
    if (t == 0) bsum[b] = sdata[0];
}

// exclusive scan of block sums (nb <= 256)
__global__ void k_scan_blocks(const int* __restrict__ bsum, int* __restrict__ boff, int nb) {
    __shared__ int sdata[256];
    int t = threadIdx.x;
    int v = (t < nb) ? bsum[t] : 0;
    sdata[t] = v; __syncthreads();
    for (int off = 1; off < 256; off <<= 1) {
        int u = (t >= off) ? sdata[t - off] : 0;
        __syncthreads();
        sdata[t] += u;
        __syncthreads();
    }
    if (t < nb) boff[t] = sdata[t] - v;   // exclusive
}

__global__ void k_scan_write(const int* __restrict__ deg, const int* __restrict__ boff,
                             int* __restrict__ rowptr, int N, int Etot) {
    __shared__ int sdata[256];
    int t = threadIdx.x, b = blockIdx.x;
    int base = b * 1024 + t * 4;
    int c[4]; int tsum = 0;
    #pragma unroll
    for (int i = 0; i < 4; i++) {
        int idx = base + i;
        c[i] = (idx < N) ? deg[idx] - 1 : 0;
        tsum += c[i];
    }
    sdata[t] = tsum; __syncthreads();
    for (int off = 1; off < 256; off <<= 1) {
        int u = (t >= off) ? sdata[t - off] : 0;
        __syncthreads();
        sdata[t] += u;
        __syncthreads();
    }
    int excl = sdata[t] - tsum + boff[b];
    #pragma unroll
    for (int i = 0; i < 4; i++) {
        int idx = base + i;
        if (idx < N) rowptr[idx] = excl;
        excl += c[i];
    }
    if (b == 0 && t == 0) rowptr[N] = Etot;
}

__global__ void k_fill(const int* __restrict__ ei, int E, const int* __restrict__ rowptr,
                       int* __restrict__ fill, int* __restrict__ col, int N) {
    int e = blockIdx.x * blockDim.x + threadIdx.x;
    if (e < E) {
        int s = ei[e], d = ei[E + e];
        if (s >= 0 && s < N && d >= 0 && d < N) {
            int slot = atomicAdd(&fill[d], 1);
            col[rowptr[d] + slot] = s;
        }
    }
}

// ---------------- GEMM: out[r][c] = dinv[r] * sum_k X[r][k] * W[k][c] ----------------
// Thread tile 4 rows x 4 cols; W and X staged in LDS (X padded +4 floats/row).

template<int D, int F, int THREADS, int RPB>
__global__ __launch_bounds__(THREADS) void k_gemm(
    const float* __restrict__ X, const float* __restrict__ W,
    const float* __restrict__ dinv, float* __restrict__ out, int N) {
    constexpr int CG = F / 4;           // col groups
    constexpr int XLD = D + 4;          // padded row stride
    __shared__ float Ws[D * F];
    __shared__ float Xs[RPB * XLD];
    int tid = threadIdx.x;
    int row0 = blockIdx.x * RPB;

    for (int i = tid; i < D * F / 4; i += THREADS)
        ((float4*)Ws)[i] = ((const float4*)W)[i];
    for (int i = tid; i < RPB * D / 4; i += THREADS) {
        int r = i / (D / 4), kk = i % (D / 4);
        int grow = row0 + r;
        float4 v = make_float4(0.f, 0.f, 0.f, 0.f);
        if (grow < N) v = *(const float4*)&X[(size_t)grow * D + kk * 4];
        *(float4*)&Xs[r * XLD + kk * 4] = v;
    }
    __syncthreads();

    int cg = tid % CG, rg = tid / CG;
    float acc[4][4] = {};
    const float* xb = &Xs[(rg * 4) * XLD];
    #pragma unroll 4
    for (int k = 0; k < D; ++k) {
        float4 w = *(float4*)&Ws[k * F + cg * 4];
        float x0 = xb[0 * XLD + k];
        float x1 = xb[1 * XLD + k];
        float x2 = xb[2 * XLD + k];
        float x3 = xb[3 * XLD + k];
        acc[0][0] += x0 * w.x; acc[0][1] += x0 * w.y; acc[0][2] += x0 * w.z; acc[0][3] += x0 * w.w;
        acc[1][0] += x1 * w.x; acc[1][1] += x1 * w.y; acc[1][2] += x1 * w.z; acc[1][3] += x1 * w.w;
        acc[2][0] += x2 * w.x; acc[2][1] += x2 * w.y; acc[2][2] += x2 * w.z; acc[2][3] += x2 * w.w;
        acc[3][0] += x3 * w.x; acc[3][1] += x3 * w.y; acc[3][2] += x3 * w.z; acc[3][3] += x3 * w.w;
    }
    #pragma unroll
    for (int i = 0; i < 4; i++) {
        int grow = row0 + rg * 4 + i;
        if (grow < N) {
            float dv = dinv[grow];
            float4 o = make_float4(acc[i][0] * dv, acc[i][1] * dv, acc[i][2] * dv, acc[i][3] * dv);
            *(float4*)&out[(size_t)grow * F + cg * 4] = o;
        }
    }
}

// ---------------- Aggregation: wave per node, lane = feature ----------------

__global__ __launch_bounds__(256) void k_agg1(
    const float* __restrict__ g1, const int* __restrict__ rowptr,
    const int* __restrict__ col, const float* __restrict__ dinv,
    const float* __restrict__ b1, float* __restrict__ out1, int N) {
    int wid = (int)((blockIdx.x * blockDim.x + threadIdx.x) >> 6);
    int lane = threadIdx.x & 63;
    if (wid >= N) return;
    int r0 = rowptr[wid], r1 = rowptr[wid + 1];
    float sum = g1[(size_t)wid * 64 + lane];   // self-loop term (g1 already has dinv[src])
    int e = r0;
    for (; e + 4 <= r1; e += 4) {
        int c0 = col[e], c1 = col[e + 1], c2 = col[e + 2], c3 = col[e + 3];
        float v0 = g1[(size_t)c0 * 64 + lane];
        float v1 = g1[(size_t)c1 * 64 + lane];
        float v2 = g1[(size_t)c2 * 64 + lane];
        float v3 = g1[(size_t)c3 * 64 + lane];
        sum += v0 + v1 + v2 + v3;
    }
    for (; e < r1; ++e) sum += g1[(size_t)col[e] * 64 + lane];
    out1[(size_t)wid * 64 + lane] = fmaxf(dinv[wid] * sum + b1[lane], 0.f);
}

__global__ __launch_bounds__(256) void k_agg2(
    const float* __restrict__ g2, const int* __restrict__ rowptr,
    const int* __restrict__ col, const float* __restrict__ dinv,
    const float* __restrict__ b2, float* __restrict__ out, int N) {
    int wid = (int)((blockIdx.x * blockDim.x + threadIdx.x) >> 6);
    int lane = threadIdx.x & 63;
    if (wid >= N) return;
    int cl = lane < 40 ? lane : 39;            // lanes >= 40 duplicate lane 39 (masked later)
    int r0 = rowptr[wid], r1 = rowptr[wid + 1];
    float sum = g2[(size_t)wid * 40 + cl];     // self-loop
    int e = r0;
    for (; e + 4 <= r1; e += 4) {
        int c0 = col[e], c1 = col[e + 1], c2 = col[e + 2], c3 = col[e + 3];
        float v0 = g2[(size_t)c0 * 40 + cl];
        float v1 = g2[(size_t)c1 * 40 + cl];
        float v2 = g2[(size_t)c2 * 40 + cl];
        float v3 = g2[(size_t)c3 * 40 + cl];
        sum += v0 + v1 + v2 + v3;
    }
    for (; e < r1; ++e) sum += g2[(size_t)col[e] * 40 + cl];
    float o = dinv[wid] * sum + b2[cl];
    // log-softmax over 40 classes (lanes >= 40 masked out of the reductions)
    float m = (lane < 40) ? o : -INFINITY;
    #pragma unroll
    for (int off = 32; off > 0; off >>= 1) m = fmaxf(m, __shfl_xor(m, off, 64));
    float p = (lane < 40) ? __expf(o - m) : 0.f;
    #pragma unroll
    for (int off = 32; off > 0; off >>= 1) p += __shfl_xor(p, off, 64);
    float l = __logf(p);
    if (lane < 40) out[(size_t)wid * 40 + lane] = o - m - l;
}

// ---------------- launch ----------------

extern "C" void kernel_launch(void* const* d_in, const int* in_sizes, int n_in,
                              void* d_out, int out_size, void* d_ws, size_t ws_size,
                              hipStream_t stream) {
    const float* x  = (const float*)d_in[0];
    const int*   ei = (const int*)d_in[1];      // [2, E] int32 (harness: integer -> int*)
    const float* W1 = (const float*)d_in[2];
    const float* b1 = (const float*)d_in[3];
    const float* W2 = (const float*)d_in[4];
    const float* b2 = (const float*)d_in[5];
    float* out = (float*)d_out;

    const int N = in_sizes[0] / 128;
    const int E = in_sizes[1] / 2;

    char* w = (char*)d_ws;
    size_t off = 0;
    auto alloc = [&](size_t bytes) -> char* {
        char* p = w + off;
        off += (bytes + 255) & ~(size_t)255;
        return p;
    };
    int*   deg    = (int*)alloc((size_t)N * 4);
    int*   fill   = (int*)alloc((size_t)N * 4);
    int*   rowptr = (int*)alloc((size_t)(N + 1) * 4);
    float* dinv   = (float*)alloc((size_t)N * 4);
    int*   bsum   = (int*)alloc(1024);
    int*   boff   = (int*)alloc(1024);
    int*   col    = (int*)alloc((size_t)E * 4);
    float* g1     = (float*)alloc((size_t)N * 64 * 4);
    float* out1   = (float*)alloc((size_t)N * 64 * 4);
    float* g2     = g1;  // g1 dead after agg1; reuse for layer-2 pre-agg

    int nb = (N + 1023) / 1024;

    k_init<<<(N + 255) / 256, 256, 0, stream>>>(deg, fill, N);
    k_count<<<(E + 255) / 256, 256, 0, stream>>>(ei, E, deg, N);
    k_blocksum<<<nb, 256, 0, stream>>>(deg, dinv, bsum, N);
    k_scan_blocks<<<1, 256, 0, stream>>>(bsum, boff, nb);
    k_scan_write<<<nb, 256, 0, stream>>>(deg, boff, rowptr, N, E);
    k_fill<<<(E + 255) / 256, 256, 0, stream>>>(ei, E, rowptr, fill, col, N);

    // layer 1: g1 = dinv * (x @ W1); agg + relu -> out1
    k_gemm<128, 64, 256, 64><<<(N + 63) / 64, 256, 0, stream>>>(x, W1, dinv, g1, N);
    k_agg1<<<(N + 3) / 4, 256, 0, stream>>>(g1, rowptr, col, dinv, b1, out1, N);

    // layer 2: g2 = dinv * (out1 @ W2); agg + bias + log_softmax -> out
    k_gemm<64, 40, 320, 128><<<(N + 127) / 128, 320, 0, stream>>>(out1, W2, dinv, g2, N);
    k_agg2<<<(N + 3) / 4, 256, 0, stream>>>(g2, rowptr, col, dinv, b2, out, N);
}

// Round 4
// 352.626 us; speedup vs baseline: 1.0925x; 1.0925x over previous
//
#include <hip/hip_runtime.h>
#include <math.h>

typedef long long i64;

// ---------------- CSR build ----------------

__global__ void k_init(int* __restrict__ deg, int* __restrict__ fill, int N) {
    int i = blockIdx.x * blockDim.x + threadIdx.x;
    if (i < N) { deg[i] = 1; fill[i] = 0; }   // deg starts at 1 (self-loop)
}

__global__ void k_count(const int* __restrict__ ei, int E, int* __restrict__ deg, int N) {
    int e = blockIdx.x * blockDim.x + threadIdx.x;
    if (e < E) {
        int d = ei[E + e];          // dst row
        if (d >= 0 && d < N) atomicAdd(&deg[d], 1);
    }
}

// per-1024-tile sums of (deg-1) + dinv computation
__global__ void k_blocksum(const int* __restrict__ deg, float* __restrict__ dinv,
                           int* __restrict__ bsum, int N) {
    __shared__ int sdata[256];
    int t = threadIdx.x, b = blockIdx.x;
    int base = b * 1024 + t * 4;
    int s = 0;
    #pragma unroll
    for (int i = 0; i < 4; i++) {
        int idx = base + i;
        if (idx < N) {
            int d = deg[idx];
            s += d - 1;
            dinv[idx] = rsqrtf((float)d);
        }
    }
    sdata[t] = s; __syncthreads();
    for (int off = 128; off > 0; off >>= 1) {
        if (t < off) sdata[t] += sdata[t + off];
        __syncthreads();
    }
    if (t == 0) bsum[b] = sdata[0];
}

// exclusive scan of block sums (nb <= 256)
__global__ void k_scan_blocks(const int* __restrict__ bsum, int* __restrict__ boff, int nb) {
    __shared__ int sdata[256];
    int t = threadIdx.x;
    int v = (t < nb) ? bsum[t] : 0;
    sdata[t] = v; __syncthreads();
    for (int off = 1; off < 256; off <<= 1) {
        int u = (t >= off) ? sdata[t - off] : 0;
        __syncthreads();
        sdata[t] += u;
        __syncthreads();
    }
    if (t < nb) boff[t] = sdata[t] - v;   // exclusive
}

__global__ void k_scan_write(const int* __restrict__ deg, const int* __restrict__ boff,
                             int* __restrict__ rowptr, int N, int Etot) {
    __shared__ int sdata[256];
    int t = threadIdx.x, b = blockIdx.x;
    int base = b * 1024 + t * 4;
    int c[4]; int tsum = 0;
    #pragma unroll
    for (int i = 0; i < 4; i++) {
        int idx = base + i;
        c[i] = (idx < N) ? deg[idx] - 1 : 0;
        tsum += c[i];
    }
    sdata[t] = tsum; __syncthreads();
    for (int off = 1; off < 256; off <<= 1) {
        int u = (t >= off) ? sdata[t - off] : 0;
        __syncthreads();
        sdata[t] += u;
        __syncthreads();
    }
    int excl = sdata[t] - tsum + boff[b];
    #pragma unroll
    for (int i = 0; i < 4; i++) {
        int idx = base + i;
        if (idx < N) rowptr[idx] = excl;
        excl += c[i];
    }
    if (b == 0 && t == 0) rowptr[N] = Etot;
}

// dst-range-partitioned CSR fill: block (chunk = bid>>3, range = bid&7).
// All blocks with the same range land on the same XCD (round-robin dispatch),
// so each col cache line is written by exactly one XCD's L2 within one pass
// -> kills the 16x write amplification seen in the flat version.
#define FILL_CHUNK 4096
__global__ __launch_bounds__(256) void k_fill2(
    const int* __restrict__ ei, int E, int N, const int* __restrict__ rowptr,
    int* __restrict__ fill, int* __restrict__ col) {
    int range = blockIdx.x & 7;
    int chunk = blockIdx.x >> 3;
    int base  = chunk * FILL_CHUNK;
    int end   = min(base + FILL_CHUNK, E);
    int lo = (int)(((i64)N * range) >> 3);
    int hi = (int)(((i64)N * (range + 1)) >> 3);
    const int* __restrict__ dstp = ei + E;
    for (int i = base + threadIdx.x; i < end; i += 256) {
        int d = dstp[i];
        if (d >= lo && d < hi) {
            int s = ei[i];
            if ((unsigned)s < (unsigned)N) {
                int slot = atomicAdd(&fill[d], 1);
                col[rowptr[d] + slot] = s;
            }
        }
    }
}

// ---------------- GEMM: out[r][c] = dinv[r] * sum_k X[r][k] * W[k][c] ----------------
// Thread tile 4 rows x 4 cols; W and X staged in LDS (X padded +4 floats/row).

template<int D, int F, int THREADS, int RPB>
__global__ __launch_bounds__(THREADS) void k_gemm(
    const float* __restrict__ X, const float* __restrict__ W,
    const float* __restrict__ dinv, float* __restrict__ out, int N) {
    constexpr int CG = F / 4;           // col groups
    constexpr int XLD = D + 4;          // padded row stride
    __shared__ float Ws[D * F];
    __shared__ float Xs[RPB * XLD];
    int tid = threadIdx.x;
    int row0 = blockIdx.x * RPB;

    for (int i = tid; i < D * F / 4; i += THREADS)
        ((float4*)Ws)[i] = ((const float4*)W)[i];
    for (int i = tid; i < RPB * D / 4; i += THREADS) {
        int r = i / (D / 4), kk = i % (D / 4);
        int grow = row0 + r;
        float4 v = make_float4(0.f, 0.f, 0.f, 0.f);
        if (grow < N) v = *(const float4*)&X[(size_t)grow * D + kk * 4];
        *(float4*)&Xs[r * XLD + kk * 4] = v;
    }
    __syncthreads();

    int cg = tid % CG, rg = tid / CG;
    float acc[4][4] = {};
    const float* xb = &Xs[(rg * 4) * XLD];
    #pragma unroll 4
    for (int k = 0; k < D; ++k) {
        float4 w = *(float4*)&Ws[k * F + cg * 4];
        float x0 = xb[0 * XLD + k];
        float x1 = xb[1 * XLD + k];
        float x2 = xb[2 * XLD + k];
        float x3 = xb[3 * XLD + k];
        acc[0][0] += x0 * w.x; acc[0][1] += x0 * w.y; acc[0][2] += x0 * w.z; acc[0][3] += x0 * w.w;
        acc[1][0] += x1 * w.x; acc[1][1] += x1 * w.y; acc[1][2] += x1 * w.z; acc[1][3] += x1 * w.w;
        acc[2][0] += x2 * w.x; acc[2][1] += x2 * w.y; acc[2][2] += x2 * w.z; acc[2][3] += x2 * w.w;
        acc[3][0] += x3 * w.x; acc[3][1] += x3 * w.y; acc[3][2] += x3 * w.z; acc[3][3] += x3 * w.w;
    }
    #pragma unroll
    for (int i = 0; i < 4; i++) {
        int grow = row0 + rg * 4 + i;
        if (grow < N) {
            float dv = dinv[grow];
            float4 o = make_float4(acc[i][0] * dv, acc[i][1] * dv, acc[i][2] * dv, acc[i][3] * dv);
            *(float4*)&out[(size_t)grow * F + cg * 4] = o;
        }
    }
}

// ---------------- Aggregation: wave per node, lane = feature ----------------

__global__ __launch_bounds__(256) void k_agg1(
    const float* __restrict__ g1, const int* __restrict__ rowptr,
    const int* __restrict__ col, const float* __restrict__ dinv,
    const float* __restrict__ b1, float* __restrict__ out1, int N) {
    int wid = (int)((blockIdx.x * blockDim.x + threadIdx.x) >> 6);
    int lane = threadIdx.x & 63;
    if (wid >= N) return;
    int r0 = rowptr[wid], r1 = rowptr[wid + 1];
    float sum = g1[(size_t)wid * 64 + lane];   // self-loop term (g1 already has dinv[src])
    int e = r0;
    for (; e + 4 <= r1; e += 4) {
        int c0 = col[e], c1 = col[e + 1], c2 = col[e + 2], c3 = col[e + 3];
        float v0 = g1[(size_t)c0 * 64 + lane];
        float v1 = g1[(size_t)c1 * 64 + lane];
        float v2 = g1[(size_t)c2 * 64 + lane];
        float v3 = g1[(size_t)c3 * 64 + lane];
        sum += v0 + v1 + v2 + v3;
    }
    for (; e < r1; ++e) sum += g1[(size_t)col[e] * 64 + lane];
    out1[(size_t)wid * 64 + lane] = fmaxf(dinv[wid] * sum + b1[lane], 0.f);
}

__global__ __launch_bounds__(256) void k_agg2(
    const float* __restrict__ g2, const int* __restrict__ rowptr,
    const int* __restrict__ col, const float* __restrict__ dinv,
    const float* __restrict__ b2, float* __restrict__ out, int N) {
    int wid = (int)((blockIdx.x * blockDim.x + threadIdx.x) >> 6);
    int lane = threadIdx.x & 63;
    if (wid >= N) return;
    int cl = lane < 40 ? lane : 39;            // lanes >= 40 duplicate lane 39 (masked later)
    int r0 = rowptr[wid], r1 = rowptr[wid + 1];
    float sum = g2[(size_t)wid * 40 + cl];     // self-loop
    int e = r0;
    for (; e + 4 <= r1; e += 4) {
        int c0 = col[e], c1 = col[e + 1], c2 = col[e + 2], c3 = col[e + 3];
        float v0 = g2[(size_t)c0 * 40 + cl];
        float v1 = g2[(size_t)c1 * 40 + cl];
        float v2 = g2[(size_t)c2 * 40 + cl];
        float v3 = g2[(size_t)c3 * 40 + cl];
        sum += v0 + v1 + v2 + v3;
    }
    for (; e < r1; ++e) sum += g2[(size_t)col[e] * 40 + cl];
    float o = dinv[wid] * sum + b2[cl];
    // log-softmax over 40 classes (lanes >= 40 masked out of the reductions)
    float m = (lane < 40) ? o : -INFINITY;
    #pragma unroll
    for (int off = 32; off > 0; off >>= 1) m = fmaxf(m, __shfl_xor(m, off, 64));
    float p = (lane < 40) ? __expf(o - m) : 0.f;
    #pragma unroll
    for (int off = 32; off > 0; off >>= 1) p += __shfl_xor(p, off, 64);
    float l = __logf(p);
    if (lane < 40) out[(size_t)wid * 40 + lane] = o - m - l;
}

// ---------------- launch ----------------

extern "C" void kernel_launch(void* const* d_in, const int* in_sizes, int n_in,
                              void* d_out, int out_size, void* d_ws, size_t ws_size,
                              hipStream_t stream) {
    const float* x  = (const float*)d_in[0];
    const int*   ei = (const int*)d_in[1];      // [2, E] int32 (harness: integer -> int*)
    const float* W1 = (const float*)d_in[2];
    const float* b1 = (const float*)d_in[3];
    const float* W2 = (const float*)d_in[4];
    const float* b2 = (const float*)d_in[5];
    float* out = (float*)d_out;

    const int N = in_sizes[0] / 128;
    const int E = in_sizes[1] / 2;

    char* w = (char*)d_ws;
    size_t off = 0;
    auto alloc = [&](size_t bytes) -> char* {
        char* p = w + off;
        off += (bytes + 255) & ~(size_t)255;
        return p;
    };
    int*   deg    = (int*)alloc((size_t)N * 4);
    int*   fill   = (int*)alloc((size_t)N * 4);
    int*   rowptr = (int*)alloc((size_t)(N + 1) * 4);
    float* dinv   = (float*)alloc((size_t)N * 4);
    int*   bsum   = (int*)alloc(1024);
    int*   boff   = (int*)alloc(1024);
    int*   col    = (int*)alloc((size_t)E * 4);
    float* g1     = (float*)alloc((size_t)N * 64 * 4);
    float* out1   = (float*)alloc((size_t)N * 64 * 4);
    float* g2     = g1;  // g1 dead after agg1; reuse for layer-2 pre-agg

    int nb = (N + 1023) / 1024;

    k_init<<<(N + 255) / 256, 256, 0, stream>>>(deg, fill, N);
    k_count<<<(E + 255) / 256, 256, 0, stream>>>(ei, E, deg, N);
    k_blocksum<<<nb, 256, 0, stream>>>(deg, dinv, bsum, N);
    k_scan_blocks<<<1, 256, 0, stream>>>(bsum, boff, nb);
    k_scan_write<<<nb, 256, 0, stream>>>(deg, boff, rowptr, N, E);

    int nchunks = (E + FILL_CHUNK - 1) / FILL_CHUNK;
    k_fill2<<<nchunks * 8, 256, 0, stream>>>(ei, E, N, rowptr, fill, col);

    // layer 1: g1 = dinv * (x @ W1); agg + relu -> out1
    k_gemm<128, 64, 256, 64><<<(N + 63) / 64, 256, 0, stream>>>(x, W1, dinv, g1, N);
    k_agg1<<<(N + 3) / 4, 256, 0, stream>>>(g1, rowptr, col, dinv, b1, out1, N);

    // layer 2: g2 = dinv * (out1 @ W2); agg + bias + log_softmax -> out
    k_gemm<64, 40, 320, 128><<<(N + 127) / 128, 320, 0, stream>>>(out1, W2, dinv, g2, N);
    k_agg2<<<(N + 3) / 4, 256, 0, stream>>>(g2, rowptr, col, dinv, b2, out, N);
}